// Round 13
// baseline (95.569 us; speedup 1.0000x reference)
//
#include <hip/hip_runtime.h>

#define C2   2.8853900817779268f    //  2*log2(e)
#define NC2 -2.8853900817779268f    // -2*log2(e)

// Kernel 1: projection + exp precompute. 512 blocks x 16 rows.
// Eq[b*512+q][h] = exp2(clamp(C2 * (queries @ Wq)[q][h], +-60)), Ek likewise (row-major).
__global__ __launch_bounds__(256) void proj_exp_kernel(
    const float* __restrict__ queries,
    const float* __restrict__ keys,
    const float* __restrict__ Wq,
    const float* __restrict__ Wk,
    float* __restrict__ Eq,
    float* __restrict__ Ek)
{
    __shared__ float w_lds[64 * 64];     // 16 KB
    __shared__ float in_lds[16 * 64];    // 4 KB

    const int t   = threadIdx.x;
    const int blk = blockIdx.x;          // 0..511
    const int r0  = blk * 16;            // virtual row among 8192
    const bool isQ = (r0 < 4096);
    const float* __restrict__ W  = isQ ? Wq : Wk;
    const float* __restrict__ in = isQ ? queries : keys;
    float* __restrict__ Eo       = isQ ? Eq : Ek;
    const int rbase = isQ ? r0 : (r0 - 4096);

#pragma unroll
    for (int i = 0; i < 16; ++i)
        w_lds[t + i * 256] = W[t + i * 256];
#pragma unroll
    for (int i = 0; i < 4; ++i)
        in_lds[t + i * 256] = in[(size_t)rbase * 64 + t + i * 256];
    __syncthreads();

    const int h  = t & 63;
    const int rg = t >> 6;               // row group 0..3 (rows rg*4 .. rg*4+3)
    const float* inr = &in_lds[rg * 4 * 64];
    float acc0 = 0.f, acc1 = 0.f, acc2 = 0.f, acc3 = 0.f;
#pragma unroll
    for (int i = 0; i < 64; i += 4) {
        float4 r0_ = *reinterpret_cast<const float4*>(inr + 0 * 64 + i);  // uniform b128
        float4 r1_ = *reinterpret_cast<const float4*>(inr + 1 * 64 + i);
        float4 r2_ = *reinterpret_cast<const float4*>(inr + 2 * 64 + i);
        float4 r3_ = *reinterpret_cast<const float4*>(inr + 3 * 64 + i);
        float w0 = w_lds[(i + 0) * 64 + h];
        float w1 = w_lds[(i + 1) * 64 + h];
        float w2 = w_lds[(i + 2) * 64 + h];
        float w3 = w_lds[(i + 3) * 64 + h];
        acc0 = fmaf(r0_.x, w0, acc0); acc0 = fmaf(r0_.y, w1, acc0);
        acc0 = fmaf(r0_.z, w2, acc0); acc0 = fmaf(r0_.w, w3, acc0);
        acc1 = fmaf(r1_.x, w0, acc1); acc1 = fmaf(r1_.y, w1, acc1);
        acc1 = fmaf(r1_.z, w2, acc1); acc1 = fmaf(r1_.w, w3, acc1);
        acc2 = fmaf(r2_.x, w0, acc2); acc2 = fmaf(r2_.y, w1, acc2);
        acc2 = fmaf(r2_.z, w2, acc2); acc2 = fmaf(r2_.w, w3, acc2);
        acc3 = fmaf(r3_.x, w0, acc3); acc3 = fmaf(r3_.y, w1, acc3);
        acc3 = fmaf(r3_.z, w2, acc3); acc3 = fmaf(r3_.w, w3, acc3);
    }
    float a[4] = {acc0, acc1, acc2, acc3};
#pragma unroll
    for (int j = 0; j < 4; ++j) {
        float x = fminf(fmaxf(a[j] * C2, -60.f), 60.f);  // bounded: products < 2^120
        Eo[(size_t)(rbase + rg * 4 + j) * 64 + h] = __builtin_amdgcn_exp2f(x);
    }
}

// Kernel 2: scores + partial softmax-denominator + partial PV for ONE k-half.
// Block = 4 waves x 64 lanes = 256 threads; __launch_bounds__(256,4): R1-proven
// config (VGPR_Count=124, no spill) at 4 blocks/CU = 16 waves/CU.
// Block (kc, b, qt) handles 8 q-rows x k in [kc*256, kc*256+256). Lane l of
// wave w owns k = kc*256 + w*64 + l: Ek row in 64 VGPRs; eq/wv via uniform-
// address ds_read_b128 broadcasts. Wave early-out iff chunk base >= vl.
// BARRIER DISCIPLINE (R12 post-timing race fix): both __syncthreads() are in
// UNIFORM control flow -- barrier 1 after staging and BEFORE the divergent
// if(wact); no barrier inside it. Active waves read eq_lds only after barrier
// 1; PV reads only self-written p_lds; cross-wave reads only after barrier 2.
// score'[q][k] = -2 * sum_h wv[h] * rcp(1 + Eq[q][h]*Ek[k][h])  (softmax-shift-invariant)
// p = exp2(score'*log2e), no max subtraction (|score'| <= 2*sum|wv| ~ 26, fp32-safe;
// masked k -> p = 0 exactly). Outputs UNNORMALIZED O-partial + denom-partial.
__global__ __launch_bounds__(256, 4) void attn_kernel(
    const float* __restrict__ Eq,
    const float* __restrict__ Ek,
    const float* __restrict__ wv,
    const float* __restrict__ V,
    const int* __restrict__ valid_lens,
    float* __restrict__ Opart,     // [kc][512][8][64]
    float* __restrict__ Dpart)     // [kc][512][8]
{
    __shared__ float p_lds[8][256];      // [q][kl]
    __shared__ float part_lds[4][8][64]; // [w][q][d]
    __shared__ float eq_lds[512];        // 8 Eq rows
    __shared__ float wv_lds[64];

    const int t   = threadIdx.x;
    const int bid = blockIdx.x;          // 0..1023
    const int kc  = bid >> 9;            // k-half 0..1
    const int rem = bid & 511;
    const int b   = rem >> 6;
    const int qt  = rem & 63;
    const int q0  = qt << 3;
    const int l   = t & 63;
    const int w   = __builtin_amdgcn_readfirstlane(threadIdx.x >> 6);  // 0..3
    const int vl  = valid_lens[b];
    const int kl  = w * 64 + l;          // local k index 0..255
    const int k   = kc * 256 + kl;       // global k
    const bool kvalid = (k < vl);
    const bool wact   = (kc * 256 + w * 64) < vl;   // wave-uniform

    // stage eq (8 rows) + wv into LDS (coalesced, one-time)
    {
        const float* eqg = Eq + (size_t)(b * 512 + q0) * 64;
        eq_lds[t]       = eqg[t];
        eq_lds[t + 256] = eqg[t + 256];
        if (t < 64) wv_lds[t] = wv[t];
    }
    __syncthreads();                     // barrier 1: UNIFORM, before divergence

    float acc[8] = {0.f, 0.f, 0.f, 0.f, 0.f, 0.f, 0.f, 0.f};

    if (wact) {
        // ---- lane-resident Ek row: 64 VGPRs, loaded once (L2-resident)
        float ek[64];
        {
            const float4* ekr = reinterpret_cast<const float4*>(Ek + (size_t)(b * 512 + k) * 64);
#pragma unroll
            for (int i = 0; i < 16; ++i) {
                float4 v = ekr[i];
                ek[4 * i + 0] = v.x; ek[4 * i + 1] = v.y;
                ek[4 * i + 2] = v.z; ek[4 * i + 3] = v.w;
            }
        }

        // ---- score: ek in VGPRs, eq/wv uniform b128 broadcasts (conflict-free)
#pragma unroll 1
        for (int q = 0; q < 8; ++q) {
            const float* eql = &eq_lds[q * 64];
            float a0 = 0.f, a1 = 0.f, a2 = 0.f, a3 = 0.f;
#pragma unroll
            for (int h = 0; h < 64; h += 8) {
                float4 e0 = *reinterpret_cast<const float4*>(eql + h);
                float4 e1 = *reinterpret_cast<const float4*>(eql + h + 4);
                float4 w0 = *reinterpret_cast<const float4*>(wv_lds + h);
                float4 w1 = *reinterpret_cast<const float4*>(wv_lds + h + 4);
                a0 = fmaf(w0.x, __builtin_amdgcn_rcpf(fmaf(e0.x, ek[h + 0], 1.f)), a0);
                a1 = fmaf(w0.y, __builtin_amdgcn_rcpf(fmaf(e0.y, ek[h + 1], 1.f)), a1);
                a2 = fmaf(w0.z, __builtin_amdgcn_rcpf(fmaf(e0.z, ek[h + 2], 1.f)), a2);
                a3 = fmaf(w0.w, __builtin_amdgcn_rcpf(fmaf(e0.w, ek[h + 3], 1.f)), a3);
                a0 = fmaf(w1.x, __builtin_amdgcn_rcpf(fmaf(e1.x, ek[h + 4], 1.f)), a0);
                a1 = fmaf(w1.y, __builtin_amdgcn_rcpf(fmaf(e1.y, ek[h + 5], 1.f)), a1);
                a2 = fmaf(w1.z, __builtin_amdgcn_rcpf(fmaf(e1.z, ek[h + 6], 1.f)), a2);
                a3 = fmaf(w1.w, __builtin_amdgcn_rcpf(fmaf(e1.w, ek[h + 7], 1.f)), a3);
            }
            float p = kvalid ? __builtin_amdgcn_exp2f(((a0 + a1) + (a2 + a3)) * NC2) : 0.f;
            p_lds[q][kl] = p;            // consecutive lanes: conflict-free b32
        }

        // ---- PV over own 64-k chunk (reads ONLY self-written p -> no barrier)
        const float* __restrict__ Vb = V + (size_t)b * 512 * 64;
        const int kb = kc * 256 + w * 64;
        const int kbl = w * 64;
#pragma unroll 4
        for (int kk = 0; kk < 64; kk += 4) {
            float4 pq[8];
#pragma unroll
            for (int q = 0; q < 8; ++q)
                pq[q] = *reinterpret_cast<const float4*>(&p_lds[q][kbl + kk]);  // uniform b128
            float v0 = Vb[(size_t)(kb + kk + 0) * 64 + l];
            float v1 = Vb[(size_t)(kb + kk + 1) * 64 + l];
            float v2 = Vb[(size_t)(kb + kk + 2) * 64 + l];
            float v3 = Vb[(size_t)(kb + kk + 3) * 64 + l];
#pragma unroll
            for (int q = 0; q < 8; ++q) {
                acc[q] = fmaf(pq[q].x, v0, acc[q]);
                acc[q] = fmaf(pq[q].y, v1, acc[q]);
                acc[q] = fmaf(pq[q].z, v2, acc[q]);
                acc[q] = fmaf(pq[q].w, v3, acc[q]);
            }
        }
    } else {
#pragma unroll
        for (int q = 0; q < 8; ++q)
            p_lds[q][kl] = 0.f;          // masked chunk: zeros for denominator
    }

#pragma unroll
    for (int q = 0; q < 8; ++q)
        part_lds[w][q][l] = acc[q];
    __syncthreads();                     // barrier 2: UNIFORM, after divergence

    // ---- reduce within block and write partials. Wave w handles q = 2w, 2w+1.
    const size_t tile = (size_t)(kc * 512 + rem);
#pragma unroll
    for (int j = 0; j < 2; ++j) {
        const int q = w * 2 + j;
        float ds = p_lds[q][l] + p_lds[q][l + 64] + p_lds[q][l + 128] + p_lds[q][l + 192];
#pragma unroll
        for (int off = 32; off > 0; off >>= 1)
            ds += __shfl_xor(ds, off);
        float o = part_lds[0][q][l] + part_lds[1][q][l]
                + part_lds[2][q][l] + part_lds[3][q][l];
        Opart[(tile * 8 + q) * 64 + l] = o;
        if (l == 0) Dpart[tile * 8 + q] = ds;
    }
}

// Kernel 3: combine the two k-halves: out = (O0+O1) * rcp(d0+d1).
__global__ __launch_bounds__(256) void combine_kernel(
    const float* __restrict__ Opart,
    const float* __restrict__ Dpart,
    float* __restrict__ out)
{
    const int bid = blockIdx.x;          // 0..511 == b*64+qt
    const int t   = threadIdx.x;
    const int l   = t & 63;
#pragma unroll
    for (int j = 0; j < 2; ++j) {
        const int q = (t >> 6) + j * 4;
        const size_t i0 = ((size_t)(0 * 512 + bid) * 8 + q) * 64 + l;
        const size_t i1 = ((size_t)(1 * 512 + bid) * 8 + q) * 64 + l;
        float o   = Opart[i0] + Opart[i1];
        float den = Dpart[(0 * 512 + bid) * 8 + q] + Dpart[(1 * 512 + bid) * 8 + q];
        out[((size_t)bid * 8 + q) * 64 + l] = o * __builtin_amdgcn_rcpf(den);
    }
}

extern "C" void kernel_launch(void* const* d_in, const int* in_sizes, int n_in,
                              void* d_out, int out_size, void* d_ws, size_t ws_size,
                              hipStream_t stream) {
    (void)in_sizes; (void)n_in; (void)out_size; (void)ws_size;
    const float* queries = (const float*)d_in[0];
    const float* keys    = (const float*)d_in[1];
    const float* values  = (const float*)d_in[2];
    const int*   vlens   = (const int*)d_in[3];
    const float* Wq      = (const float*)d_in[4];
    const float* Wk      = (const float*)d_in[5];
    const float* wv      = (const float*)d_in[6];
    float* out = (float*)d_out;

    float* Eq    = (float*)d_ws;              // 262144 floats = 1 MB
    float* Ek    = Eq + 262144;               // 1 MB
    float* Opart = Ek + 262144;               // 2*512*8*64 = 524288 floats = 2 MB
    float* Dpart = Opart + 524288;            // 2*512*8 = 8192 floats

    proj_exp_kernel<<<512, 256, 0, stream>>>(queries, keys, Wq, Wk, Eq, Ek);
    attn_kernel<<<1024, 256, 0, stream>>>(Eq, Ek, wv, values, vlens, Opart, Dpart);
    combine_kernel<<<512, 256, 0, stream>>>(Opart, Dpart, out);
}